// Round 5
// baseline (102.411 us; speedup 1.0000x reference)
//
#include <hip/hip_runtime.h>

// 2D Gaussian splatting renderer, MI355X. R5.
// N=4096 gaussians, 512x512x3 fp32 image, 64 tiles of 64x64 px.
//
// R5 theory: render's blend loop was LDS-pipe-bound (2x ds_read_b128 + b32
// broadcast per gaussian per wave, ~30 cyc on the CU-shared LDS pipe x 8
// waves/CU ~ 15us) plus chunk barriers and an 8x-redundant per-tile cull.
// Changes:
//  - gs_gather (64 blocks): cull+compact ONCE per tile, write gathered params
//    contiguously to global ws (ta4/tb4/tc1 + counts).
//  - gs_render: no LDS, no barriers. Inner loop reads ta4[tile*4096+k] at a
//    wave-uniform affine address -> SMEM s_load (or single-line coalesced
//    vector load); ~5.4KB/tile lives in L1/L2. Pure-VALU loop ~58 cyc/SIMD
//    per gaussian (2 waves), 2px/thread, 512 blocks interleaved across tiles.

#define N_G    4096
#define W_IMG  512
#define TL_    64
#define NT_    8
#define NTILES 64
#define MAXG   4096   // per-tile list capacity (worst case: all gaussians)

// ws layout (bytes):
//   [0,      65536) : float4 a4[N_G]  = {px, py, -ia/2, -ibc/2}  (depth-sorted)
//   [65536, 131072) : float4 b4[N_G]  = {-idd/2, op, cr, cg}
//   [131072,147456) : float  c1[N_G]  = cb
//   [147456,163840) : float  rad[N_G]
//   [163840, +4MB ) : float4 ta4[NTILES][MAXG]   gathered per-tile params
//   [ +4MB,  +8MB ) : float4 tb4[NTILES][MAXG]
//   [ +8MB,  +9MB ) : float  tc1[NTILES][MAXG]
//   [ +9MB, +9MB+256): int   counts[NTILES]

__global__ __launch_bounds__(256)
void gs_preprocess(const float* __restrict__ pos2d,
                   const float* __restrict__ cov2d,
                   const float* __restrict__ opacity,
                   const float* __restrict__ color,
                   float4* __restrict__ a4,
                   float4* __restrict__ b4,
                   float* __restrict__ c1,
                   float* __restrict__ rad_out) {
    __shared__ __align__(16) float s_depth[N_G];
    const int t = threadIdx.x;

    for (int k = t; k < N_G; k += 256)
        s_depth[k] = pos2d[k * 3 + 2];
    __syncthreads();

    const int g = t >> 4;                  // 16 gaussian slots per block
    const int s = t & 15;                  // 16-way j partition per gaussian
    const int i = blockIdx.x * 16 + g;     // 256 blocks x 16 = 4096
    const float di = s_depth[i];

    // j4 = s + 16k: 16 lanes hit 16 distinct 4-bank groups (free 2-way b128).
    const float4* s_d4 = (const float4*)s_depth;
    int rank = 0;
    #pragma unroll 8
    for (int k = 0; k < 64; ++k) {
        const int j4 = s + 16 * k;
        const float4 d = s_d4[j4];
        const int j = 4 * j4;
        rank += (d.x < di) || (d.x == di && (j + 0) < i);   // stable argsort
        rank += (d.y < di) || (d.y == di && (j + 1) < i);
        rank += (d.z < di) || (d.z == di && (j + 2) < i);
        rank += (d.w < di) || (d.w == di && (j + 3) < i);
    }
    rank += __shfl_xor(rank, 1);
    rank += __shfl_xor(rank, 2);
    rank += __shfl_xor(rank, 4);
    rank += __shfl_xor(rank, 8);

    if (s == 0) {
        const float px = pos2d[i * 3 + 0];
        const float py = pos2d[i * 3 + 1];
        const float a = cov2d[i * 4 + 0];
        const float b = cov2d[i * 4 + 1];
        const float c = cov2d[i * 4 + 2];
        const float d = cov2d[i * 4 + 3];

        const float trace = a + d;
        const float det = a * d - b * c;
        const float tmp = trace * trace - 4.0f * det;
        const float term2 = 0.5f * sqrtf(fmaxf(tmp, 0.0f));
        const float radius = 3.0f * sqrtf(fmaxf(0.5f * trace - term2, 0.5f * trace + term2));
        const float inv_det = 1.0f / det;
        const float ia  = d * inv_det;
        const float ibc = (-b * inv_det) + (-c * inv_det);  // match ref's ib+ic rounding
        const float idd = a * inv_det;

        const float op = opacity[i];
        const float cr = fmaxf(color[i * 3 + 0] + 0.5f, 0.0f);
        const float cg = fmaxf(color[i * 3 + 1] + 0.5f, 0.0f);
        const float cb = fmaxf(color[i * 3 + 2] + 0.5f, 0.0f);

        a4[rank] = make_float4(px, py, -0.5f * ia, -0.5f * ibc);
        b4[rank] = make_float4(-0.5f * idd, op, cr, cg);
        c1[rank] = cb;
        rad_out[rank] = radius;
    }
}

__global__ __launch_bounds__(256)
void gs_gather(const float4* __restrict__ a4,
               const float4* __restrict__ b4,
               const float* __restrict__ c1,
               const float* __restrict__ rad,
               float4* __restrict__ ta4,
               float4* __restrict__ tb4,
               float* __restrict__ tc1,
               int* __restrict__ counts) {
    // One block per tile. Cull + cross-wave-stable compaction into s_list
    // (ascending sorted index == depth order), then gathered param writeout.
    __shared__ unsigned short s_list[N_G];
    __shared__ int s_wcnt[4];

    const int tile = blockIdx.x;
    const int tx = tile / NT_;
    const int ty = tile % NT_;
    const float left = (float)(tx * TL_);
    const float top  = (float)(ty * TL_);
    const int t = threadIdx.x;
    const int wave = t >> 6;
    const int lane = t & 63;

    unsigned int bits = 0;
    int wcnt = 0;
    #pragma unroll 4
    for (int it = 0; it < 16; ++it) {
        const int g = wave * 1024 + it * 64 + lane;
        const float4 A = a4[g];
        const float r = rad[g];
        const bool m = (A.x + r >= left) && (A.x - r < left + (float)TL_) &&
                       (A.y + r >= top)  && (A.y - r < top  + (float)TL_);
        bits |= (m ? 1u : 0u) << it;
        wcnt += __popcll(__ballot(m));
    }
    if (lane == 0) s_wcnt[wave] = wcnt;
    __syncthreads();
    const int c0 = s_wcnt[0], c1_ = s_wcnt[1], c2 = s_wcnt[2], c3 = s_wcnt[3];
    const int total = c0 + c1_ + c2 + c3;
    int base = (wave > 0 ? c0 : 0) + (wave > 1 ? c1_ : 0) + (wave > 2 ? c2 : 0);
    #pragma unroll 4
    for (int it = 0; it < 16; ++it) {
        const bool m = (bits >> it) & 1u;
        const unsigned long long bal = __ballot(m);
        const int prefix = __popcll(bal & ((1ULL << lane) - 1ULL));
        if (m) s_list[base + prefix] = (unsigned short)(wave * 1024 + it * 64 + lane);
        base += __popcll(bal);
    }
    __syncthreads();

    float4* da = ta4 + tile * MAXG;
    float4* db = tb4 + tile * MAXG;
    float*  dc = tc1 + tile * MAXG;
    for (int i = t; i < total; i += 256) {
        const int g = s_list[i];
        da[i] = a4[g];
        db[i] = b4[g];
        dc[i] = c1[g];
    }
    if (t == 0) counts[tile] = total;
}

__global__ __launch_bounds__(256)
void gs_render(const float4* __restrict__ ta4,
               const float4* __restrict__ tb4,
               const float* __restrict__ tc1,
               const int* __restrict__ counts,
               float* __restrict__ out) {
    // tile = blockIdx & 63 (interleaved: co-resident blocks differ in tile;
    // the 8 blocks of a tile map to the same XCD under mod-8 dispatch).
    // Block covers 8 px in X, 64 in Y. Thread t: Y = ty*64 + (t&63),
    // X = tx*64 + sub*8 + (t>>6)*2 + {0,1}. Lane==Y -> coalesced stores.
    // No LDS, no barriers: inner loop reads are wave-uniform affine -> SMEM.
    const int tile = blockIdx.x & 63;
    const int sub  = blockIdx.x >> 6;      // 0..7
    const int tx = tile / NT_;
    const int ty = tile % NT_;
    const int t = threadIdx.x;

    const int X0 = tx * TL_ + sub * 8 + (t >> 6) * 2;
    const int Y  = ty * TL_ + (t & 63);
    const float fX = (float)X0;
    const float fY = (float)Y;

    const float4* ta = ta4 + tile * MAXG;
    const float4* tb = tb4 + tile * MAXG;
    const float*  tc = tc1 + tile * MAXG;
    const int count = counts[tile];

    float T0 = 1.f, T1 = 1.f;
    float R0 = 0.f, G0 = 0.f, B0 = 0.f;
    float R1 = 0.f, G1 = 0.f, B1 = 0.f;

    #pragma unroll 4
    for (int k = 0; k < count; ++k) {
        const float4 A  = ta[k];   // px, py, -ia/2, -ibc/2
        const float4 Bv = tb[k];   // -idd/2, op, cr, cg
        const float cbv = tc[k];
        const float dy      = fY - A.y;
        const float dx0     = fX - A.x;
        const float nibcdy  = A.w * dy;
        const float nidddy2 = Bv.x * dy * dy;
#define PX_BLEND(i, T, Rr, Gg, Bb)                                            \
        {                                                                     \
            const float dx = dx0 + (float)i;                                  \
            const float q = A.z * dx * dx + nibcdy * dx + nidddy2;            \
            const float alpha =                                               \
                fminf(fmaxf(Bv.y * __expf(q), 0.01f), 0.99f);                 \
            const float w_ = alpha * T;                                       \
            Rr += w_ * Bv.z; Gg += w_ * Bv.w; Bb += w_ * cbv;                 \
            T = T - alpha * T;                                                \
        }
        PX_BLEND(0, T0, R0, G0, B0)
        PX_BLEND(1, T1, R1, G1, B1)
#undef PX_BLEND
    }

    const int o0 = (X0 * W_IMG + Y) * 3;
    out[o0 + 0] = R0; out[o0 + 1] = G0; out[o0 + 2] = B0;
    out[o0 + W_IMG * 3 + 0] = R1; out[o0 + W_IMG * 3 + 1] = G1; out[o0 + W_IMG * 3 + 2] = B1;
}

extern "C" void kernel_launch(void* const* d_in, const int* in_sizes, int n_in,
                              void* d_out, int out_size, void* d_ws, size_t ws_size,
                              hipStream_t stream) {
    const float* pos2d   = (const float*)d_in[0];
    const float* cov2d   = (const float*)d_in[1];
    const float* opacity = (const float*)d_in[2];
    const float* color   = (const float*)d_in[3];
    float* out = (float*)d_out;

    char* ws = (char*)d_ws;
    float4* a4 = (float4*)(ws);
    float4* b4 = (float4*)(ws + 65536);
    float*  c1 = (float*)(ws + 131072);
    float*  rd = (float*)(ws + 147456);
    char* tbase = ws + 163840;
    float4* ta4 = (float4*)(tbase);
    float4* tb4 = (float4*)(tbase + (size_t)NTILES * MAXG * 16);
    float*  tc1 = (float*)(tbase + (size_t)NTILES * MAXG * 32);
    int* counts = (int*)(tbase + (size_t)NTILES * MAXG * 36);

    gs_preprocess<<<N_G / 16, 256, 0, stream>>>(pos2d, cov2d, opacity, color,
                                                a4, b4, c1, rd);
    gs_gather<<<NTILES, 256, 0, stream>>>(a4, b4, c1, rd, ta4, tb4, tc1, counts);
    gs_render<<<NTILES * 8, 256, 0, stream>>>(ta4, tb4, tc1, counts, out);
}